// Round 13
// baseline (267.136 us; speedup 1.0000x reference)
//
#include <hip/hip_runtime.h>
#include <math.h>

#define HW   256
#define TR   16     // tile rows (owned)
#define TC   32     // tile cols (owned)
#define NBLK 8192   // 64 frames * 16 row-tiles * 8 col-tiles
#define BR   24     // hblur rows staged (TR + 2*4)
#define HC   36     // hblur/blur cols (TC + 2*2), multiple of 4
#define VR   20     // blur rows (TR + 2*2)
#define GR   18     // grad rows (TR + 2*1)
#define GC   34     // grad cols (TC + 2*1) -- logical
#define GCP  35     // s_grad row stride (odd => decorrelated banks)
#define NHALO 100   // perimeter of GR x GC grid: 2*34 + 2*16
#define NG1  (BR * 9)   // 216 float4-groups in s_tmp  (<= 256: no loop)
#define NG2  (VR * 9)   // 180 float4-groups in s_blur (<= 256: no loop)

typedef float f32x2 __attribute__((ext_vector_type(2)));

namespace {
// Gaussian(5, std=1) computed in float64 then cast, matching _gaussian_1d
constexpr double kE2  = 0.13533528323661269189;  // exp(-2)
constexpr double kE05 = 0.60653065971263342360;  // exp(-0.5)
constexpr double kSum = 1.0 + 2.0 * kE2 + 2.0 * kE05;
constexpr float G0f = (float)(kE2 / kSum);
constexpr float G1f = (float)(kE05 / kSum);
constexpr float G2f = (float)(1.0 / kSum);
constexpr float T1  = 0.41421356237309503f;   // tan(22.5 deg)
constexpr float T2  = 2.41421356237309503f;   // tan(67.5 deg)
__device__ __forceinline__ float fast_sqrtf(float x) {
    return __builtin_amdgcn_sqrtf(x);          // raw v_sqrt_f32 (1-2 ulp)
}
__device__ __forceinline__ int iclamp(int v, int lo, int hi) {
    return v < lo ? lo : (v > hi ? hi : v);
}
__device__ __forceinline__ f32x2 mk2(float x, float y) {
    f32x2 r; r.x = x; r.y = y; return r;
}
}

// EDGE=true: full bounds handling. EDGE=false: tile + all halos strictly
// inside the image -> every check folds away (branch-free fast path).
// Both images are processed CONCURRENTLY: each phase carries two independent
// dependency chains (doubles per-wave ILP), and barriers are shared.
// NOTE: requires the VGPR budget of __launch_bounds__(256, 5) (102 VGPR);
// at (256, 8) (64 VGPR) the dual chains spill to scratch (R11: 14.8 MB
// WRITE_SIZE). Occupancy is LDS-capped at ~5 blocks/CU regardless.
template<bool EDGE>
__device__ __forceinline__ float tile_body(
    const float* __restrict__ bA, const float* __restrict__ bB,
    const int tid, const int ty0, const int tx0,
    float* __restrict__ s_tmpA,  float* __restrict__ s_tmpB,
    float* __restrict__ s_blurA, float* __restrict__ s_blurB,
    float* __restrict__ s_gradA, float* __restrict__ s_gradB)
{
    const int ox  = tid & 31;            // owned column within tile
    const int oy0 = (tid >> 5) * 2;      // owned rows oy0, oy0+1

    const f32x2 g0p = mk2(G0f, G0f), g1p = mk2(G1f, G1f), g2p = mk2(G2f, G2f);

    // ---- hoisted staging geometry (all named scalars; NO per-thread arrays)
    const int  q9  = tid / 9;            // group row
    const int  c4  = (tid - 9 * q9) * 4; // group start col (elements)
    const int  stw = q9 * HC + c4;       // s_tmp / s_blur write index (float4)
    const bool a1on = (tid < NG1);
    const int  y1   = ty0 - 4 + q9;
    const bool y1ok = !EDGE || ((unsigned)y1 < HW);
    const int  x0   = tx0 - 4 + c4;
    const int  ga   = y1 * HW + (EDGE ? iclamp(x0, 0, HW - 4) : x0);
    const int  gb   = y1 * HW + (EDGE ? iclamp(x0 + 4, 0, HW - 4) : x0 + 4);
    const bool a2on = (tid < NG2);
    const int  y2   = ty0 - 2 + q9;
    const bool y2ok = !EDGE || ((unsigned)y2 < HW);
    const int  xb2  = tx0 - 2 + c4;
    const bool ok0 = !EDGE || ((unsigned)(xb2 + 0) < HW);
    const bool ok1 = !EDGE || ((unsigned)(xb2 + 1) < HW);
    const bool ok2 = !EDGE || ((unsigned)(xb2 + 2) < HW);
    const bool ok3 = !EDGE || ((unsigned)(xb2 + 3) < HW);
    // A3a: sobel window base (blur rows oy0+1 .. oy0+4, cols ox+1..ox+3)
    const int  b3  = (oy0 + 1) * HC + (ox + 1);
    const int  gw  = (oy0 + 1) * GCP + (ox + 1);  // s_grad center, k=0
    // halo element (r,cc) for threads < NHALO (perimeter of GR x GC)
    int h_r = 0, h_cc = 0;
    if (tid < 34)        { h_r = 0;            h_cc = tid; }
    else if (tid < 68)   { h_r = GR - 1;       h_cc = tid - 34; }
    else if (tid < 84)   { h_r = tid - 68 + 1; h_cc = 0; }
    else if (tid < NHALO){ h_r = tid - 84 + 1; h_cc = GC - 1; }
    const bool has_halo = (tid < NHALO);
    const bool h_in = !EDGE || (((unsigned)(ty0 - 1 + h_r) < HW) &&
                                ((unsigned)(tx0 - 1 + h_cc) < HW));
    const int  h_b  = h_r * HC + h_cc;            // s_blur read base
    const int  h_gw = h_r * GCP + h_cc;           // s_grad write

    // per-image accumulators (named, no arrays)
    f32x2 gxsA = mk2(0.f,0.f), gysA = mk2(0.f,0.f), gmsA = mk2(0.f,0.f);
    f32x2 gxsB = mk2(0.f,0.f), gysB = mk2(0.f,0.f), gmsB = mk2(0.f,0.f);
    float hmA = 0.f, hmB = 0.f;

    for (int c = 0; c < 3; ++c) {
        const float* pA = bA + c * (HW * HW);
        const float* pB = bB + c * (HW * HW);

        // ---- A1: horizontal gaussian, BOTH images (4 loads in flight)
        if (a1on) {
            float4 oA = make_float4(0.f,0.f,0.f,0.f);
            float4 oB = make_float4(0.f,0.f,0.f,0.f);
            if (y1ok) {
                const float4 aA = *(const float4*)(pA + ga);
                const float4 bA4 = *(const float4*)(pA + gb);
                const float4 aB = *(const float4*)(pB + ga);
                const float4 bB4 = *(const float4*)(pB + gb);
                {
                    const f32x2 p0 = mk2(aA.x, aA.y), p1 = mk2(aA.y, aA.z);
                    const f32x2 p2 = mk2(aA.z, aA.w), p3 = mk2(aA.w, bA4.x);
                    const f32x2 p4 = mk2(bA4.x, bA4.y);
                    const f32x2 q3 = mk2(bA4.y, bA4.z), q4 = mk2(bA4.z, bA4.w);
                    const f32x2 oxy = g0p*p0 + g1p*p1 + g2p*p2 + g1p*p3 + g0p*p4;
                    const f32x2 ozw = g0p*p2 + g1p*p3 + g2p*p4 + g1p*q3 + g0p*q4;
                    oA.x = oxy.x; oA.y = oxy.y; oA.z = ozw.x; oA.w = ozw.y;
                }
                {
                    const f32x2 p0 = mk2(aB.x, aB.y), p1 = mk2(aB.y, aB.z);
                    const f32x2 p2 = mk2(aB.z, aB.w), p3 = mk2(aB.w, bB4.x);
                    const f32x2 p4 = mk2(bB4.x, bB4.y);
                    const f32x2 q3 = mk2(bB4.y, bB4.z), q4 = mk2(bB4.z, bB4.w);
                    const f32x2 oxy = g0p*p0 + g1p*p1 + g2p*p2 + g1p*p3 + g0p*p4;
                    const f32x2 ozw = g0p*p2 + g1p*p3 + g2p*p4 + g1p*q3 + g0p*q4;
                    oB.x = oxy.x; oB.y = oxy.y; oB.z = ozw.x; oB.w = ozw.y;
                }
                if (EDGE) {
                    if (x0 < 0) {                 // left image edge (x0 == -4)
                        oA.x = G0f*aA.x;
                        oA.y = G1f*aA.x + G0f*aA.y;
                        oA.z = G2f*aA.x + G1f*aA.y + G0f*aA.z;
                        oA.w = G1f*aA.x + G2f*aA.y + G1f*aA.z + G0f*aA.w;
                        oB.x = G0f*aB.x;
                        oB.y = G1f*aB.x + G0f*aB.y;
                        oB.z = G2f*aB.x + G1f*aB.y + G0f*aB.z;
                        oB.w = G1f*aB.x + G2f*aB.y + G1f*aB.z + G0f*aB.w;
                    } else if (x0 > HW - 8) {     // right image edge (x0 == 252)
                        oA.x = G0f*aA.x + G1f*aA.y + G2f*aA.z + G1f*aA.w;
                        oA.y = G0f*aA.y + G1f*aA.z + G2f*aA.w;
                        oA.z = G0f*aA.z + G1f*aA.w;
                        oA.w = G0f*aA.w;
                        oB.x = G0f*aB.x + G1f*aB.y + G2f*aB.z + G1f*aB.w;
                        oB.y = G0f*aB.y + G1f*aB.z + G2f*aB.w;
                        oB.z = G0f*aB.z + G1f*aB.w;
                        oB.w = G0f*aB.w;
                    }
                }
            }
            *(float4*)&s_tmpA[stw] = oA;
            *(float4*)&s_tmpB[stw] = oB;
        }
        __syncthreads();

        // ---- A2: vertical gaussian, BOTH images
        if (a2on) {
            float4 vA = make_float4(0.f,0.f,0.f,0.f);
            float4 vB = make_float4(0.f,0.f,0.f,0.f);
            if (y2ok) {
                {
                    const float4 t0 = *(const float4*)&s_tmpA[stw];
                    const float4 t1 = *(const float4*)&s_tmpA[stw + 1 * HC];
                    const float4 t2 = *(const float4*)&s_tmpA[stw + 2 * HC];
                    const float4 t3 = *(const float4*)&s_tmpA[stw + 3 * HC];
                    const float4 t4 = *(const float4*)&s_tmpA[stw + 4 * HC];
                    const f32x2 vxy = g0p*mk2(t0.x,t0.y) + g1p*mk2(t1.x,t1.y)
                                    + g2p*mk2(t2.x,t2.y) + g1p*mk2(t3.x,t3.y)
                                    + g0p*mk2(t4.x,t4.y);
                    const f32x2 vzw = g0p*mk2(t0.z,t0.w) + g1p*mk2(t1.z,t1.w)
                                    + g2p*mk2(t2.z,t2.w) + g1p*mk2(t3.z,t3.w)
                                    + g0p*mk2(t4.z,t4.w);
                    vA.x = ok0 ? vxy.x : 0.f;
                    vA.y = ok1 ? vxy.y : 0.f;
                    vA.z = ok2 ? vzw.x : 0.f;
                    vA.w = ok3 ? vzw.y : 0.f;
                }
                {
                    const float4 t0 = *(const float4*)&s_tmpB[stw];
                    const float4 t1 = *(const float4*)&s_tmpB[stw + 1 * HC];
                    const float4 t2 = *(const float4*)&s_tmpB[stw + 2 * HC];
                    const float4 t3 = *(const float4*)&s_tmpB[stw + 3 * HC];
                    const float4 t4 = *(const float4*)&s_tmpB[stw + 4 * HC];
                    const f32x2 vxy = g0p*mk2(t0.x,t0.y) + g1p*mk2(t1.x,t1.y)
                                    + g2p*mk2(t2.x,t2.y) + g1p*mk2(t3.x,t3.y)
                                    + g0p*mk2(t4.x,t4.y);
                    const f32x2 vzw = g0p*mk2(t0.z,t0.w) + g1p*mk2(t1.z,t1.w)
                                    + g2p*mk2(t2.z,t2.w) + g1p*mk2(t3.z,t3.w)
                                    + g0p*mk2(t4.z,t4.w);
                    vB.x = ok0 ? vxy.x : 0.f;
                    vB.y = ok1 ? vxy.y : 0.f;
                    vB.z = ok2 ? vzw.x : 0.f;
                    vB.w = ok3 ? vzw.y : 0.f;
                }
            }
            *(float4*)&s_blurA[stw] = vA;
            *(float4*)&s_blurB[stw] = vB;
        }
        __syncthreads();

        // ---- A3a: interior sobel via row-sum factoring, BOTH images
        {
            float cdA0, cdA1, cdA2, cdA3, rsA0, rsA1, rsA2, rsA3;
            float cdB0, cdB1, cdB2, cdB3, rsB0, rsB1, rsB2, rsB3;
            {
                const float* b = &s_blurA[b3];
                float bl, bc, br;
                bl=b[0]; bc=b[1]; br=b[2]; cdA0=bl-br; rsA0=bl+2.f*bc+br; b+=HC;
                bl=b[0]; bc=b[1]; br=b[2]; cdA1=bl-br; rsA1=bl+2.f*bc+br; b+=HC;
                bl=b[0]; bc=b[1]; br=b[2]; cdA2=bl-br; rsA2=bl+2.f*bc+br; b+=HC;
                bl=b[0]; bc=b[1]; br=b[2]; cdA3=bl-br; rsA3=bl+2.f*bc+br;
            }
            {
                const float* b = &s_blurB[b3];
                float bl, bc, br;
                bl=b[0]; bc=b[1]; br=b[2]; cdB0=bl-br; rsB0=bl+2.f*bc+br; b+=HC;
                bl=b[0]; bc=b[1]; br=b[2]; cdB1=bl-br; rsB1=bl+2.f*bc+br; b+=HC;
                bl=b[0]; bc=b[1]; br=b[2]; cdB2=bl-br; rsB2=bl+2.f*bc+br; b+=HC;
                bl=b[0]; bc=b[1]; br=b[2]; cdB3=bl-br; rsB3=bl+2.f*bc+br;
            }
            const f32x2 gxA = mk2(cdA0, cdA1) + 2.0f * mk2(cdA1, cdA2) + mk2(cdA2, cdA3);
            const f32x2 gyA = mk2(rsA0, rsA1) - mk2(rsA2, rsA3);
            const f32x2 gxB = mk2(cdB0, cdB1) + 2.0f * mk2(cdB1, cdB2) + mk2(cdB2, cdB3);
            const f32x2 gyB = mk2(rsB0, rsB1) - mk2(rsB2, rsB3);
            gxsA += gxA; gysA += gyA;
            gxsB += gxB; gysB += gyB;
            const f32x2 mA = gxA * gxA + gyA * gyA;
            const f32x2 mB = gxB * gxB + gyB * gyB;
            gmsA += mk2(fast_sqrtf(mA.x), fast_sqrtf(mA.y));
            gmsB += mk2(fast_sqrtf(mB.x), fast_sqrtf(mB.y));
            s_gradA[gw]       = gmsA.x;
            s_gradA[gw + GCP] = gmsA.y;
            s_gradB[gw]       = gmsB.x;
            s_gradB[gw + GCP] = gmsB.y;
        }

        // ---- A3b: halo sobel (perimeter), BOTH images
        if (has_halo) {
            float gmA = 0.0f, gmB = 0.0f;
            if (h_in) {
                {
                    const float* b = &s_blurA[h_b];
                    const float b00 = b[0],      b01 = b[1],        b02 = b[2];
                    const float b10 = b[HC],                        b12 = b[HC + 2];
                    const float b20 = b[2*HC],   b21 = b[2*HC + 1], b22 = b[2*HC + 2];
                    const float gx = (b00 + 2.0f*b10 + b20) - (b02 + 2.0f*b12 + b22);
                    const float gy = (b00 + 2.0f*b01 + b02) - (b20 + 2.0f*b21 + b22);
                    gmA = fast_sqrtf(gx * gx + gy * gy);
                }
                {
                    const float* b = &s_blurB[h_b];
                    const float b00 = b[0],      b01 = b[1],        b02 = b[2];
                    const float b10 = b[HC],                        b12 = b[HC + 2];
                    const float b20 = b[2*HC],   b21 = b[2*HC + 1], b22 = b[2*HC + 2];
                    const float gx = (b00 + 2.0f*b10 + b20) - (b02 + 2.0f*b12 + b22);
                    const float gy = (b00 + 2.0f*b01 + b02) - (b20 + 2.0f*b21 + b22);
                    gmB = fast_sqrtf(gx * gx + gy * gy);
                }
            }
            hmA += gmA; hmB += gmB;
            s_gradA[h_gw] = hmA;
            s_gradB[h_gw] = hmB;
        }
        // no sync here: next A1 writes only s_tmp*, whose readers (A2) are
        // fenced by the post-A1 sync of the next channel.
    }
    __syncthreads();  // both grads complete for all channels

    // ---- Phase B: axis-based NMS + threshold, both images; diff accumulated
    float acc = 0.0f;
    #pragma unroll
    for (int k = 0; k < 2; ++k) {
        const int ci = gw + k * GCP;
        float eA, eB;
        {
            const float gc = (k == 0) ? gmsA.x : gmsA.y;
            const float gx = (k == 0) ? gxsA.x : gxsA.y;
            const float gy = (k == 0) ? gysA.x : gysA.y;
            const float ax = fabsf(gx), ay = fabsf(gy);
            int dy, dx;
            if (ay <= T1 * ax)      { dy = 0; dx = 1; }
            else if (ay >= T2 * ax) { dy = 1; dx = 0; }
            else                    { dy = 1; dx = ((gx > 0.0f) == (gy > 0.0f)) ? 1 : -1; }
            const float pos = gc - s_gradA[ci + dy * GCP + dx];
            const float neg = gc - s_gradA[ci - dy * GCP - dx];
            const float thin = (fminf(pos, neg) > 0.0f) ? gc : 0.0f;
            eA = (thin < 2.0f) ? 0.0f : thin;
        }
        {
            const float gc = (k == 0) ? gmsB.x : gmsB.y;
            const float gx = (k == 0) ? gxsB.x : gxsB.y;
            const float gy = (k == 0) ? gysB.x : gysB.y;
            const float ax = fabsf(gx), ay = fabsf(gy);
            int dy, dx;
            if (ay <= T1 * ax)      { dy = 0; dx = 1; }
            else if (ay >= T2 * ax) { dy = 1; dx = 0; }
            else                    { dy = 1; dx = ((gx > 0.0f) == (gy > 0.0f)) ? 1 : -1; }
            const float pos = gc - s_gradB[ci + dy * GCP + dx];
            const float neg = gc - s_gradB[ci - dy * GCP - dx];
            const float thin = (fminf(pos, neg) > 0.0f) ? gc : 0.0f;
            eB = (thin < 2.0f) ? 0.0f : thin;
        }
        acc += fabsf(eA - eB);
    }
    return acc;
}

__global__ __launch_bounds__(256, 5)
void canny_tile_kernel(const float* __restrict__ imgA,
                       const float* __restrict__ imgB,
                       float* __restrict__ partials,
                       unsigned int* __restrict__ counter,
                       float* __restrict__ out)
{
    __shared__ __align__(16) float s_tmpA[BR * HC];
    __shared__ __align__(16) float s_tmpB[BR * HC];
    __shared__ __align__(16) float s_blurA[VR * HC];
    __shared__ __align__(16) float s_blurB[VR * HC];
    __shared__ float s_gradA[GR * GCP];
    __shared__ float s_gradB[GR * GCP];
    __shared__ float s_red[4];
    __shared__ unsigned int s_ticket;

    const int tid = threadIdx.x;
    // XCD-chunked bijective swizzle (NBLK % 8 == 0)
    const int bid = blockIdx.x;
    const int lg  = (bid & 7) * (NBLK / 8) + (bid >> 3);
    const int n    = lg >> 7;            // frame 0..63
    const int tile = lg & 127;
    const int rt   = tile >> 3;          // row-tile 0..15
    const int ct   = tile & 7;           // col-tile 0..7
    const int ty0  = rt * TR;
    const int tx0  = ct * TC;

    const float* bA = imgA + (size_t)n * 3 * (HW * HW);
    const float* bB = imgB + (size_t)n * 3 * (HW * HW);

    // interior: all staged rows/cols strictly inside the image
    const bool interior = (rt >= 1) && (rt <= 14) && (ct >= 1) && (ct <= 6);

    float acc;
    if (interior) acc = tile_body<false>(bA, bB, tid, ty0, tx0,
                                         s_tmpA, s_tmpB, s_blurA, s_blurB,
                                         s_gradA, s_gradB);
    else          acc = tile_body<true >(bA, bB, tid, ty0, tx0,
                                         s_tmpA, s_tmpB, s_blurA, s_blurB,
                                         s_gradA, s_gradB);

    // ---- deterministic block reduction
    #pragma unroll
    for (int off = 32; off > 0; off >>= 1) acc += __shfl_down(acc, off, 64);
    if ((tid & 63) == 0) s_red[tid >> 6] = acc;
    __syncthreads();
    if (tid == 0) {
        partials[bid] = (s_red[0] + s_red[1]) + (s_red[2] + s_red[3]);
        __threadfence();                         // release: partials visible device-wide
        s_ticket = atomicAdd(counter, 1u);       // device-scope by default
        if (s_ticket == NBLK - 1) __threadfence(); // acquire before reading partials
    }
    __syncthreads();

    // ---- last block reduces all partials (value deterministic: fixed order)
    if (s_ticket == NBLK - 1) {
        float v = 0.0f;
        #pragma unroll
        for (int j = 0; j < 8; ++j) {
            const float4 a = *(const float4*)&partials[4 * (tid + 256 * j)];
            v += (a.x + a.y) + (a.z + a.w);
        }
        #pragma unroll
        for (int off = 32; off > 0; off >>= 1) v += __shfl_down(v, off, 64);
        if ((tid & 63) == 0) s_red[tid >> 6] = v;
        __syncthreads();
        if (tid == 0)
            out[0] = ((s_red[0] + s_red[1]) + (s_red[2] + s_red[3])) * (1.0f / 4194304.0f);
    }
}

extern "C" void kernel_launch(void* const* d_in, const int* in_sizes, int n_in,
                              void* d_out, int out_size, void* d_ws, size_t ws_size,
                              hipStream_t stream)
{
    const float* tgt     = (const float*)d_in[0];  // data_input  [4,16,3,256,256]
    const float* out_img = (const float*)d_in[1];  // model_output
    float* partials = (float*)d_ws;                          // 8192 floats
    unsigned int* counter = (unsigned int*)((char*)d_ws + NBLK * sizeof(float));

    hipMemsetAsync(counter, 0, sizeof(unsigned int), stream);
    canny_tile_kernel<<<NBLK, 256, 0, stream>>>(out_img, tgt, partials, counter,
                                                (float*)d_out);
}

// Round 14
// 46.698 us; speedup vs baseline: 5.7205x; 5.7205x over previous
//
#include <hip/hip_runtime.h>
#include <math.h>

#define HW   256
#define TR   16     // tile rows (owned)
#define TC   32     // tile cols (owned)
#define NBLK 8192   // 64 frames * 16 row-tiles * 8 col-tiles
#define BR   24     // hblur rows staged (TR + 2*4)
#define HC   36     // hblur/blur cols (TC + 2*2), multiple of 4
#define VR   20     // blur rows (TR + 2*2)
#define GR   18     // grad rows (TR + 2*1)
#define GC   34     // grad cols (TC + 2*1) -- logical
#define GCP  35     // s_grad row stride (odd => decorrelated banks)
#define NHALO 100   // perimeter of GR x GC grid: 2*34 + 2*16
#define NG1  (BR * 9)   // 216 float4-groups in s_tmp  (<= 256: no loop)
#define NG2  (VR * 9)   // 180 float4-groups in s_blur (<= 256: no loop)

typedef float f32x2 __attribute__((ext_vector_type(2)));

namespace {
// Gaussian(5, std=1) computed in float64 then cast, matching _gaussian_1d
constexpr double kE2  = 0.13533528323661269189;  // exp(-2)
constexpr double kE05 = 0.60653065971263342360;  // exp(-0.5)
constexpr double kSum = 1.0 + 2.0 * kE2 + 2.0 * kE05;
constexpr float G0f = (float)(kE2 / kSum);
constexpr float G1f = (float)(kE05 / kSum);
constexpr float G2f = (float)(1.0 / kSum);
constexpr float T1  = 0.41421356237309503f;   // tan(22.5 deg)
constexpr float T2  = 2.41421356237309503f;   // tan(67.5 deg)
__device__ __forceinline__ float fast_sqrtf(float x) {
    return __builtin_amdgcn_sqrtf(x);          // raw v_sqrt_f32 (1-2 ulp)
}
__device__ __forceinline__ int iclamp(int v, int lo, int hi) {
    return v < lo ? lo : (v > hi ? hi : v);
}
__device__ __forceinline__ f32x2 mk2(float x, float y) {
    f32x2 r; r.x = x; r.y = y; return r;
}
}

// EDGE=true: full bounds handling. EDGE=false: tile + all halos strictly
// inside the image -> every check folds away (branch-free fast path).
// Both images are processed CONCURRENTLY: each phase carries two independent
// dependency chains (doubles per-wave ILP), and barriers are shared.
// NOTE: requires the VGPR budget of __launch_bounds__(256, 5) (102 VGPR);
// at (256, 8) (64 VGPR) the dual chains spill to scratch (R11: 14.8 MB
// WRITE_SIZE). Occupancy is LDS-capped at ~5 blocks/CU regardless.
// NOTE 2 (R13 lesson): do NOT fuse the final reduction via per-block
// __threadfence + atomic ticket — device-scope fences hit the non-coherent
// per-XCD L2s and cost ~300 us across 8192 blocks (47 -> 267 us). The
// separate 1-block reduce dispatch costs only ~3-5 us.
template<bool EDGE>
__device__ __forceinline__ float tile_body(
    const float* __restrict__ bA, const float* __restrict__ bB,
    const int tid, const int ty0, const int tx0,
    float* __restrict__ s_tmpA,  float* __restrict__ s_tmpB,
    float* __restrict__ s_blurA, float* __restrict__ s_blurB,
    float* __restrict__ s_gradA, float* __restrict__ s_gradB)
{
    const int ox  = tid & 31;            // owned column within tile
    const int oy0 = (tid >> 5) * 2;      // owned rows oy0, oy0+1

    const f32x2 g0p = mk2(G0f, G0f), g1p = mk2(G1f, G1f), g2p = mk2(G2f, G2f);

    // ---- hoisted staging geometry (all named scalars; NO per-thread arrays)
    const int  q9  = tid / 9;            // group row
    const int  c4  = (tid - 9 * q9) * 4; // group start col (elements)
    const int  stw = q9 * HC + c4;       // s_tmp / s_blur write index (float4)
    const bool a1on = (tid < NG1);
    const int  y1   = ty0 - 4 + q9;
    const bool y1ok = !EDGE || ((unsigned)y1 < HW);
    const int  x0   = tx0 - 4 + c4;
    const int  ga   = y1 * HW + (EDGE ? iclamp(x0, 0, HW - 4) : x0);
    const int  gb   = y1 * HW + (EDGE ? iclamp(x0 + 4, 0, HW - 4) : x0 + 4);
    const bool a2on = (tid < NG2);
    const int  y2   = ty0 - 2 + q9;
    const bool y2ok = !EDGE || ((unsigned)y2 < HW);
    const int  xb2  = tx0 - 2 + c4;
    const bool ok0 = !EDGE || ((unsigned)(xb2 + 0) < HW);
    const bool ok1 = !EDGE || ((unsigned)(xb2 + 1) < HW);
    const bool ok2 = !EDGE || ((unsigned)(xb2 + 2) < HW);
    const bool ok3 = !EDGE || ((unsigned)(xb2 + 3) < HW);
    // A3a: sobel window base (blur rows oy0+1 .. oy0+4, cols ox+1..ox+3)
    const int  b3  = (oy0 + 1) * HC + (ox + 1);
    const int  gw  = (oy0 + 1) * GCP + (ox + 1);  // s_grad center, k=0
    // halo element (r,cc) for threads < NHALO (perimeter of GR x GC)
    int h_r = 0, h_cc = 0;
    if (tid < 34)        { h_r = 0;            h_cc = tid; }
    else if (tid < 68)   { h_r = GR - 1;       h_cc = tid - 34; }
    else if (tid < 84)   { h_r = tid - 68 + 1; h_cc = 0; }
    else if (tid < NHALO){ h_r = tid - 84 + 1; h_cc = GC - 1; }
    const bool has_halo = (tid < NHALO);
    const bool h_in = !EDGE || (((unsigned)(ty0 - 1 + h_r) < HW) &&
                                ((unsigned)(tx0 - 1 + h_cc) < HW));
    const int  h_b  = h_r * HC + h_cc;            // s_blur read base
    const int  h_gw = h_r * GCP + h_cc;           // s_grad write

    // per-image accumulators (named, no arrays)
    f32x2 gxsA = mk2(0.f,0.f), gysA = mk2(0.f,0.f), gmsA = mk2(0.f,0.f);
    f32x2 gxsB = mk2(0.f,0.f), gysB = mk2(0.f,0.f), gmsB = mk2(0.f,0.f);
    float hmA = 0.f, hmB = 0.f;

    for (int c = 0; c < 3; ++c) {
        const float* pA = bA + c * (HW * HW);
        const float* pB = bB + c * (HW * HW);

        // ---- A1: horizontal gaussian, BOTH images (4 loads in flight)
        if (a1on) {
            float4 oA = make_float4(0.f,0.f,0.f,0.f);
            float4 oB = make_float4(0.f,0.f,0.f,0.f);
            if (y1ok) {
                const float4 aA = *(const float4*)(pA + ga);
                const float4 bA4 = *(const float4*)(pA + gb);
                const float4 aB = *(const float4*)(pB + ga);
                const float4 bB4 = *(const float4*)(pB + gb);
                {
                    const f32x2 p0 = mk2(aA.x, aA.y), p1 = mk2(aA.y, aA.z);
                    const f32x2 p2 = mk2(aA.z, aA.w), p3 = mk2(aA.w, bA4.x);
                    const f32x2 p4 = mk2(bA4.x, bA4.y);
                    const f32x2 q3 = mk2(bA4.y, bA4.z), q4 = mk2(bA4.z, bA4.w);
                    const f32x2 oxy = g0p*p0 + g1p*p1 + g2p*p2 + g1p*p3 + g0p*p4;
                    const f32x2 ozw = g0p*p2 + g1p*p3 + g2p*p4 + g1p*q3 + g0p*q4;
                    oA.x = oxy.x; oA.y = oxy.y; oA.z = ozw.x; oA.w = ozw.y;
                }
                {
                    const f32x2 p0 = mk2(aB.x, aB.y), p1 = mk2(aB.y, aB.z);
                    const f32x2 p2 = mk2(aB.z, aB.w), p3 = mk2(aB.w, bB4.x);
                    const f32x2 p4 = mk2(bB4.x, bB4.y);
                    const f32x2 q3 = mk2(bB4.y, bB4.z), q4 = mk2(bB4.z, bB4.w);
                    const f32x2 oxy = g0p*p0 + g1p*p1 + g2p*p2 + g1p*p3 + g0p*p4;
                    const f32x2 ozw = g0p*p2 + g1p*p3 + g2p*p4 + g1p*q3 + g0p*q4;
                    oB.x = oxy.x; oB.y = oxy.y; oB.z = ozw.x; oB.w = ozw.y;
                }
                if (EDGE) {
                    if (x0 < 0) {                 // left image edge (x0 == -4)
                        oA.x = G0f*aA.x;
                        oA.y = G1f*aA.x + G0f*aA.y;
                        oA.z = G2f*aA.x + G1f*aA.y + G0f*aA.z;
                        oA.w = G1f*aA.x + G2f*aA.y + G1f*aA.z + G0f*aA.w;
                        oB.x = G0f*aB.x;
                        oB.y = G1f*aB.x + G0f*aB.y;
                        oB.z = G2f*aB.x + G1f*aB.y + G0f*aB.z;
                        oB.w = G1f*aB.x + G2f*aB.y + G1f*aB.z + G0f*aB.w;
                    } else if (x0 > HW - 8) {     // right image edge (x0 == 252)
                        oA.x = G0f*aA.x + G1f*aA.y + G2f*aA.z + G1f*aA.w;
                        oA.y = G0f*aA.y + G1f*aA.z + G2f*aA.w;
                        oA.z = G0f*aA.z + G1f*aA.w;
                        oA.w = G0f*aA.w;
                        oB.x = G0f*aB.x + G1f*aB.y + G2f*aB.z + G1f*aB.w;
                        oB.y = G0f*aB.y + G1f*aB.z + G2f*aB.w;
                        oB.z = G0f*aB.z + G1f*aB.w;
                        oB.w = G0f*aB.w;
                    }
                }
            }
            *(float4*)&s_tmpA[stw] = oA;
            *(float4*)&s_tmpB[stw] = oB;
        }
        __syncthreads();

        // ---- A2: vertical gaussian, BOTH images
        if (a2on) {
            float4 vA = make_float4(0.f,0.f,0.f,0.f);
            float4 vB = make_float4(0.f,0.f,0.f,0.f);
            if (y2ok) {
                {
                    const float4 t0 = *(const float4*)&s_tmpA[stw];
                    const float4 t1 = *(const float4*)&s_tmpA[stw + 1 * HC];
                    const float4 t2 = *(const float4*)&s_tmpA[stw + 2 * HC];
                    const float4 t3 = *(const float4*)&s_tmpA[stw + 3 * HC];
                    const float4 t4 = *(const float4*)&s_tmpA[stw + 4 * HC];
                    const f32x2 vxy = g0p*mk2(t0.x,t0.y) + g1p*mk2(t1.x,t1.y)
                                    + g2p*mk2(t2.x,t2.y) + g1p*mk2(t3.x,t3.y)
                                    + g0p*mk2(t4.x,t4.y);
                    const f32x2 vzw = g0p*mk2(t0.z,t0.w) + g1p*mk2(t1.z,t1.w)
                                    + g2p*mk2(t2.z,t2.w) + g1p*mk2(t3.z,t3.w)
                                    + g0p*mk2(t4.z,t4.w);
                    vA.x = ok0 ? vxy.x : 0.f;
                    vA.y = ok1 ? vxy.y : 0.f;
                    vA.z = ok2 ? vzw.x : 0.f;
                    vA.w = ok3 ? vzw.y : 0.f;
                }
                {
                    const float4 t0 = *(const float4*)&s_tmpB[stw];
                    const float4 t1 = *(const float4*)&s_tmpB[stw + 1 * HC];
                    const float4 t2 = *(const float4*)&s_tmpB[stw + 2 * HC];
                    const float4 t3 = *(const float4*)&s_tmpB[stw + 3 * HC];
                    const float4 t4 = *(const float4*)&s_tmpB[stw + 4 * HC];
                    const f32x2 vxy = g0p*mk2(t0.x,t0.y) + g1p*mk2(t1.x,t1.y)
                                    + g2p*mk2(t2.x,t2.y) + g1p*mk2(t3.x,t3.y)
                                    + g0p*mk2(t4.x,t4.y);
                    const f32x2 vzw = g0p*mk2(t0.z,t0.w) + g1p*mk2(t1.z,t1.w)
                                    + g2p*mk2(t2.z,t2.w) + g1p*mk2(t3.z,t3.w)
                                    + g0p*mk2(t4.z,t4.w);
                    vB.x = ok0 ? vxy.x : 0.f;
                    vB.y = ok1 ? vxy.y : 0.f;
                    vB.z = ok2 ? vzw.x : 0.f;
                    vB.w = ok3 ? vzw.y : 0.f;
                }
            }
            *(float4*)&s_blurA[stw] = vA;
            *(float4*)&s_blurB[stw] = vB;
        }
        __syncthreads();

        // ---- A3a: interior sobel via row-sum factoring, BOTH images
        {
            float cdA0, cdA1, cdA2, cdA3, rsA0, rsA1, rsA2, rsA3;
            float cdB0, cdB1, cdB2, cdB3, rsB0, rsB1, rsB2, rsB3;
            {
                const float* b = &s_blurA[b3];
                float bl, bc, br;
                bl=b[0]; bc=b[1]; br=b[2]; cdA0=bl-br; rsA0=bl+2.f*bc+br; b+=HC;
                bl=b[0]; bc=b[1]; br=b[2]; cdA1=bl-br; rsA1=bl+2.f*bc+br; b+=HC;
                bl=b[0]; bc=b[1]; br=b[2]; cdA2=bl-br; rsA2=bl+2.f*bc+br; b+=HC;
                bl=b[0]; bc=b[1]; br=b[2]; cdA3=bl-br; rsA3=bl+2.f*bc+br;
            }
            {
                const float* b = &s_blurB[b3];
                float bl, bc, br;
                bl=b[0]; bc=b[1]; br=b[2]; cdB0=bl-br; rsB0=bl+2.f*bc+br; b+=HC;
                bl=b[0]; bc=b[1]; br=b[2]; cdB1=bl-br; rsB1=bl+2.f*bc+br; b+=HC;
                bl=b[0]; bc=b[1]; br=b[2]; cdB2=bl-br; rsB2=bl+2.f*bc+br; b+=HC;
                bl=b[0]; bc=b[1]; br=b[2]; cdB3=bl-br; rsB3=bl+2.f*bc+br;
            }
            const f32x2 gxA = mk2(cdA0, cdA1) + 2.0f * mk2(cdA1, cdA2) + mk2(cdA2, cdA3);
            const f32x2 gyA = mk2(rsA0, rsA1) - mk2(rsA2, rsA3);
            const f32x2 gxB = mk2(cdB0, cdB1) + 2.0f * mk2(cdB1, cdB2) + mk2(cdB2, cdB3);
            const f32x2 gyB = mk2(rsB0, rsB1) - mk2(rsB2, rsB3);
            gxsA += gxA; gysA += gyA;
            gxsB += gxB; gysB += gyB;
            const f32x2 mA = gxA * gxA + gyA * gyA;
            const f32x2 mB = gxB * gxB + gyB * gyB;
            gmsA += mk2(fast_sqrtf(mA.x), fast_sqrtf(mA.y));
            gmsB += mk2(fast_sqrtf(mB.x), fast_sqrtf(mB.y));
            s_gradA[gw]       = gmsA.x;
            s_gradA[gw + GCP] = gmsA.y;
            s_gradB[gw]       = gmsB.x;
            s_gradB[gw + GCP] = gmsB.y;
        }

        // ---- A3b: halo sobel (perimeter), BOTH images
        if (has_halo) {
            float gmA = 0.0f, gmB = 0.0f;
            if (h_in) {
                {
                    const float* b = &s_blurA[h_b];
                    const float b00 = b[0],      b01 = b[1],        b02 = b[2];
                    const float b10 = b[HC],                        b12 = b[HC + 2];
                    const float b20 = b[2*HC],   b21 = b[2*HC + 1], b22 = b[2*HC + 2];
                    const float gx = (b00 + 2.0f*b10 + b20) - (b02 + 2.0f*b12 + b22);
                    const float gy = (b00 + 2.0f*b01 + b02) - (b20 + 2.0f*b21 + b22);
                    gmA = fast_sqrtf(gx * gx + gy * gy);
                }
                {
                    const float* b = &s_blurB[h_b];
                    const float b00 = b[0],      b01 = b[1],        b02 = b[2];
                    const float b10 = b[HC],                        b12 = b[HC + 2];
                    const float b20 = b[2*HC],   b21 = b[2*HC + 1], b22 = b[2*HC + 2];
                    const float gx = (b00 + 2.0f*b10 + b20) - (b02 + 2.0f*b12 + b22);
                    const float gy = (b00 + 2.0f*b01 + b02) - (b20 + 2.0f*b21 + b22);
                    gmB = fast_sqrtf(gx * gx + gy * gy);
                }
            }
            hmA += gmA; hmB += gmB;
            s_gradA[h_gw] = hmA;
            s_gradB[h_gw] = hmB;
        }
        // no sync here: next A1 writes only s_tmp*, whose readers (A2) are
        // fenced by the post-A1 sync of the next channel.
    }
    __syncthreads();  // both grads complete for all channels

    // ---- Phase B: axis-based NMS + threshold, both images; diff accumulated
    float acc = 0.0f;
    #pragma unroll
    for (int k = 0; k < 2; ++k) {
        const int ci = gw + k * GCP;
        float eA, eB;
        {
            const float gc = (k == 0) ? gmsA.x : gmsA.y;
            const float gx = (k == 0) ? gxsA.x : gxsA.y;
            const float gy = (k == 0) ? gysA.x : gysA.y;
            const float ax = fabsf(gx), ay = fabsf(gy);
            int dy, dx;
            if (ay <= T1 * ax)      { dy = 0; dx = 1; }
            else if (ay >= T2 * ax) { dy = 1; dx = 0; }
            else                    { dy = 1; dx = ((gx > 0.0f) == (gy > 0.0f)) ? 1 : -1; }
            const float pos = gc - s_gradA[ci + dy * GCP + dx];
            const float neg = gc - s_gradA[ci - dy * GCP - dx];
            const float thin = (fminf(pos, neg) > 0.0f) ? gc : 0.0f;
            eA = (thin < 2.0f) ? 0.0f : thin;
        }
        {
            const float gc = (k == 0) ? gmsB.x : gmsB.y;
            const float gx = (k == 0) ? gxsB.x : gxsB.y;
            const float gy = (k == 0) ? gysB.x : gysB.y;
            const float ax = fabsf(gx), ay = fabsf(gy);
            int dy, dx;
            if (ay <= T1 * ax)      { dy = 0; dx = 1; }
            else if (ay >= T2 * ax) { dy = 1; dx = 0; }
            else                    { dy = 1; dx = ((gx > 0.0f) == (gy > 0.0f)) ? 1 : -1; }
            const float pos = gc - s_gradB[ci + dy * GCP + dx];
            const float neg = gc - s_gradB[ci - dy * GCP - dx];
            const float thin = (fminf(pos, neg) > 0.0f) ? gc : 0.0f;
            eB = (thin < 2.0f) ? 0.0f : thin;
        }
        acc += fabsf(eA - eB);
    }
    return acc;
}

__global__ __launch_bounds__(256, 5)
void canny_tile_kernel(const float* __restrict__ imgA,
                       const float* __restrict__ imgB,
                       float* __restrict__ partials)
{
    __shared__ __align__(16) float s_tmpA[BR * HC];
    __shared__ __align__(16) float s_tmpB[BR * HC];
    __shared__ __align__(16) float s_blurA[VR * HC];
    __shared__ __align__(16) float s_blurB[VR * HC];
    __shared__ float s_gradA[GR * GCP];
    __shared__ float s_gradB[GR * GCP];
    __shared__ float s_red[4];

    const int tid = threadIdx.x;
    // XCD-chunked bijective swizzle (NBLK % 8 == 0)
    const int bid = blockIdx.x;
    const int lg  = (bid & 7) * (NBLK / 8) + (bid >> 3);
    const int n    = lg >> 7;            // frame 0..63
    const int tile = lg & 127;
    const int rt   = tile >> 3;          // row-tile 0..15
    const int ct   = tile & 7;           // col-tile 0..7
    const int ty0  = rt * TR;
    const int tx0  = ct * TC;

    const float* bA = imgA + (size_t)n * 3 * (HW * HW);
    const float* bB = imgB + (size_t)n * 3 * (HW * HW);

    // interior: all staged rows/cols strictly inside the image
    const bool interior = (rt >= 1) && (rt <= 14) && (ct >= 1) && (ct <= 6);

    float acc;
    if (interior) acc = tile_body<false>(bA, bB, tid, ty0, tx0,
                                         s_tmpA, s_tmpB, s_blurA, s_blurB,
                                         s_gradA, s_gradB);
    else          acc = tile_body<true >(bA, bB, tid, ty0, tx0,
                                         s_tmpA, s_tmpB, s_blurA, s_blurB,
                                         s_gradA, s_gradB);

    // ---- deterministic block reduction
    #pragma unroll
    for (int off = 32; off > 0; off >>= 1) acc += __shfl_down(acc, off, 64);
    if ((tid & 63) == 0) s_red[tid >> 6] = acc;
    __syncthreads();
    if (tid == 0) partials[bid] = (s_red[0] + s_red[1]) + (s_red[2] + s_red[3]);
}

__global__ void final_reduce_kernel(const float* __restrict__ partials,
                                    float* __restrict__ out)
{
    __shared__ float s_red[16];
    const int tid = threadIdx.x;  // 1024 threads, 8192 partials
    const float4 a = *(const float4*)&partials[4 * tid];
    const float4 b = *(const float4*)&partials[4 * tid + 4096];
    float v = ((a.x + a.y) + (a.z + a.w)) + ((b.x + b.y) + (b.z + b.w));
    #pragma unroll
    for (int off = 32; off > 0; off >>= 1) v += __shfl_down(v, off, 64);
    if ((tid & 63) == 0) s_red[tid >> 6] = v;
    __syncthreads();
    if (tid == 0) {
        float s = 0.0f;
        #pragma unroll
        for (int j = 0; j < 16; ++j) s += s_red[j];
        out[0] = s * (1.0f / 4194304.0f);
    }
}

extern "C" void kernel_launch(void* const* d_in, const int* in_sizes, int n_in,
                              void* d_out, int out_size, void* d_ws, size_t ws_size,
                              hipStream_t stream)
{
    const float* tgt     = (const float*)d_in[0];  // data_input  [4,16,3,256,256]
    const float* out_img = (const float*)d_in[1];  // model_output
    float* partials = (float*)d_ws;                // 8192 floats

    canny_tile_kernel<<<NBLK, 256, 0, stream>>>(out_img, tgt, partials);
    final_reduce_kernel<<<1, 1024, 0, stream>>>(partials, (float*)d_out);
}